// Round 1
// 285.559 us; speedup vs baseline: 1.0583x; 1.0583x over previous
//
#include <hip/hip_runtime.h>
#include <hip/hip_bf16.h>

#define B_ 4
#define N_ 4096
#define D_ 1024
#define H_ 16
#define E_ 256
#define HD_ 64

typedef __attribute__((ext_vector_type(8))) short bf16x8;
typedef __attribute__((ext_vector_type(4))) short shortx4;
typedef __attribute__((ext_vector_type(4))) float floatx4;

__device__ inline short f2bf(float f) {
  __hip_bfloat16 h = __float2bfloat16(f);
  short s;
  __builtin_memcpy(&s, &h, 2);
  return s;
}

// async global->LDS, 16 bytes per lane (dest = wave-uniform base + lane*16)
__device__ inline void gld_lds16(const short* g, short* l) {
  __builtin_amdgcn_global_load_lds(
      (const __attribute__((address_space(1))) void*)g,
      (__attribute__((address_space(3))) void*)l, 16, 0, 0);
}

// ---------------- transpose + cast fp32 -> bf16 (shared body) ----------------
template <bool CAST_COPY>
__device__ inline void transpose_body(const float* __restrict__ src,
                                      short* __restrict__ dstT,
                                      short* __restrict__ dstC,
                                      int R, int C) {
  __shared__ float tile[32][33];
  int c0 = blockIdx.x * 32;
  int r0 = blockIdx.y * 32;
  int tx = threadIdx.x;   // 0..31
  int ty = threadIdx.y;   // 0..7
#pragma unroll
  for (int i = 0; i < 4; ++i) {
    int r = ty * 4 + i;
    float v = src[(size_t)(r0 + r) * C + (c0 + tx)];
    tile[r][tx] = v;
    if constexpr (CAST_COPY)
      dstC[(size_t)(r0 + r) * C + (c0 + tx)] = f2bf(v);
  }
  __syncthreads();
#pragma unroll
  for (int i = 0; i < 4; ++i) {
    int c = ty * 4 + i;
    dstT[(size_t)(c0 + c) * R + (r0 + tx)] = f2bf(tile[tx][c]);
  }
}

__global__ void transpose_x_kernel(const float* __restrict__ x,
                                   short* __restrict__ xtb,
                                   short* __restrict__ xb) {
  int b = blockIdx.z;
  transpose_body<true>(x + (size_t)b * N_ * D_, xtb + (size_t)b * D_ * N_,
                       xb + (size_t)b * N_ * D_, N_, D_);
}

__global__ void transpose_w_kernel(const float* __restrict__ Wq,
                                   const float* __restrict__ Wk,
                                   const float* __restrict__ Wv,
                                   short* __restrict__ WqT,
                                   short* __restrict__ WkT,
                                   short* __restrict__ WvT) {
  int z = blockIdx.z;
  const float* src = (z == 0) ? Wq : (z == 1) ? Wk : Wv;
  short* dst = (z == 0) ? WqT : (z == 1) ? WkT : WvT;
  transpose_body<false>(src, dst, nullptr, D_, D_);
}

__global__ void transpose_p_kernel(const float* __restrict__ proj,
                                   short* __restrict__ projT) {
  transpose_body<false>(proj, projT, nullptr, N_, E_);
}

// ---------------- fp32 -> bf16 cast (for split-K result) ----------------
__global__ void cast_f32_bf16_kernel(const float* __restrict__ in,
                                     short* __restrict__ out) {
  int i = (blockIdx.x * 256 + threadIdx.x) * 4;
  const float4 v = *(const float4*)(in + i);
  shortx4 o;
  o[0] = f2bf(v.x); o[1] = f2bf(v.y); o[2] = f2bf(v.z); o[3] = f2bf(v.w);
  *(shortx4*)(out + i) = o;
}

// ===========================================================================
// 256x256 8-phase bf16 GEMM (T1+T2+T3+T4+T5), C[M,Nc] = A[M,K] * Bt[Nc,K]^T
// 512 thr = 8 waves (2M x 4N); per-wave C = 128x64. BK=64 split in kk halves.
// LDS 128 KiB = 2buf x {A,B} x {kk0,kk1} x [256 rows][32 cols] bf16 slabs.
// Schedule (per iter = tiles t,t+1; buf0=even tile, buf1=odd):
//   ph1: rd b0.A0 + b0.B0(nt01) | stage b1.B1<-t+1 | mfma c01 (kk0)
//   ph2: rd b0.B0(nt23)         | stage b0.A0<-t+2 | mfma c23
//   ph3: rd b0.A1 + b0.B1(nt01) | stage b0.B0<-t+2 | mfma c01 (kk1)
//   ph4: rd b0.B1(nt23)         | stage b0.A1<-t+2 | mfma c23 | vmcnt(6)
//   ph5..8: same on buf1 (stages: b0.B1<-t+2, b1.A0<-t+3, b1.B0<-t+3,
//           b1.A1<-t+3) | vmcnt(6) at ph8
// Every slab's last ds_read is >=1 barrier before its re-stage; vmcnt(6)
// keeps exactly the 3 newest half-tiles in flight (counted, never 0).
// LDS swizzle: byte a ^= ((a>>7)&7)<<4 (involution; bits 4-6 from row bits
// 1-3) applied to BOTH the pre-swizzled global_load_lds source and ds_read.
// ===========================================================================
__device__ inline bf16x8 frag256(const short* slab, int row, int q) {
  int a = (row << 6) + (q << 4);
  a ^= ((a >> 7) & 7) << 4;
  return *(const bf16x8*)(slab + (a >> 1));
}

#define G_BAR() __builtin_amdgcn_s_barrier()
#define G_LGK0() asm volatile("s_waitcnt lgkmcnt(0)" ::: "memory")
#define G_VM6() asm volatile("s_waitcnt vmcnt(6)" ::: "memory")
#define G_VM0() asm volatile("s_waitcnt vmcnt(0)" ::: "memory")
#define G_PRIO1() __builtin_amdgcn_s_setprio(1)
#define G_PRIO0() __builtin_amdgcn_s_setprio(0)

__global__ __launch_bounds__(512) void gemm256_bt_kernel(
    const short* __restrict__ Ag, const short* __restrict__ Btg,
    short* __restrict__ Cg, int M, int Nc, int K) {
  __shared__ short lds[65536];  // 128 KiB: 8 slabs of 8192 shorts
#define SLAB(b, o, kk2) (lds + ((((((b) << 1) | (o)) << 1) | (kk2)) * 8192))

  int tid = threadIdx.x;
  int lane = tid & 63;
  int w = tid >> 6;
  int l16 = lane & 15;
  int quad = lane >> 4;
  int wm = w >> 2;   // 0..1
  int wn = w & 3;    // 0..3

  // XCD-bijective swizzle (gridDim.x % 8 == 0 here: 256 blocks)
  int nwg = gridDim.x;
  int cpx = nwg >> 3;
  int bid = blockIdx.x;
  int swz = (bid & 7) * cpx + (bid >> 3);
  int ntile_m = M >> 8;
  int tm = swz % ntile_m;
  int tn = swz / ntile_m;
  int m0 = tm * 256, n0 = tn * 256;

  const short* gA = Ag + (size_t)m0 * K;
  const short* gB = Btg + (size_t)n0 * K;

  // pre-swizzled staging source offsets (shared by A and B; same ld = K)
  int a0 = tid * 16;
  int w0 = a0 ^ (((a0 >> 7) & 7) << 4);
  int a1 = (tid + 512) * 16;
  int w1 = a1 ^ (((a1 >> 7) & 7) << 4);
  size_t so0 = (size_t)(w0 >> 6) * K + ((w0 & 63) >> 1);
  size_t so1 = (size_t)(w1 >> 6) * K + ((w1 & 63) >> 1);

#define STAGE(b, o, kk2, gsrc)                      \
  do {                                              \
    short* _sl = SLAB(b, o, kk2);                   \
    gld_lds16((gsrc) + so0, _sl + tid * 8);         \
    gld_lds16((gsrc) + so1, _sl + 4096 + tid * 8);  \
  } while (0)

  floatx4 acc[8][4];
#pragma unroll
  for (int i = 0; i < 8; ++i)
#pragma unroll
    for (int j = 0; j < 4; ++j) acc[i][j] = (floatx4){0.f, 0.f, 0.f, 0.f};

  bf16x8 af[8], bfr0, bfr1;

#define READ_A(bu, kk2)                                             \
  do {                                                              \
    const short* _sa = SLAB(bu, 0, kk2);                            \
    _Pragma("unroll") for (int mt = 0; mt < 8; ++mt)                \
        af[mt] = frag256(_sa, wm * 128 + mt * 16 + l16, quad);      \
  } while (0)
#define READ_B(bu, kk2, ntb)                                        \
  do {                                                              \
    const short* _sb = SLAB(bu, 1, kk2);                            \
    bfr0 = frag256(_sb, wn * 64 + (ntb)*16 + l16, quad);            \
    bfr1 = frag256(_sb, wn * 64 + (ntb)*16 + 16 + l16, quad);       \
  } while (0)
#define MFMA2(c0, c1)                                                          \
  do {                                                                         \
    _Pragma("unroll") for (int mt = 0; mt < 8; ++mt) {                         \
      acc[mt][c0] =                                                            \
          __builtin_amdgcn_mfma_f32_16x16x32_bf16(af[mt], bfr0, acc[mt][c0],   \
                                                  0, 0, 0);                    \
      acc[mt][c1] =                                                            \
          __builtin_amdgcn_mfma_f32_16x16x32_bf16(af[mt], bfr1, acc[mt][c1],   \
                                                  0, 0, 0);                    \
    }                                                                          \
  } while (0)

  // prologue: tile0 (4 halves) + tile1 (A0,B0,A1); keep newest 3 in flight
  STAGE(0, 0, 0, gA);
  STAGE(0, 1, 0, gB);
  STAGE(0, 0, 1, gA + 32);
  STAGE(0, 1, 1, gB + 32);
  STAGE(1, 0, 0, gA + 64);
  STAGE(1, 1, 0, gB + 64);
  STAGE(1, 0, 1, gA + 96);
  G_VM6();
  G_BAR();

  const int NI = K >> 7;  // iterations of 2 K-tiles
#pragma unroll 1
  for (int it = 0; it < NI - 1; ++it) {
    int t0 = it * 2;
    const short* gAt2 = gA + (t0 + 2) * 64;
    const short* gBt2 = gB + (t0 + 2) * 64;
    const short* gAt3 = gA + (t0 + 3) * 64;
    const short* gBt3 = gB + (t0 + 3) * 64;
    // ph1
    READ_A(0, 0); READ_B(0, 0, 0);
    STAGE(1, 1, 1, gB + (t0 + 1) * 64 + 32);
    G_BAR(); G_LGK0(); G_PRIO1(); MFMA2(0, 1); G_PRIO0(); G_BAR();
    // ph2
    READ_B(0, 0, 2);
    STAGE(0, 0, 0, gAt2);
    G_BAR(); G_LGK0(); G_PRIO1(); MFMA2(2, 3); G_PRIO0(); G_BAR();
    // ph3
    READ_A(0, 1); READ_B(0, 1, 0);
    STAGE(0, 1, 0, gBt2);
    G_BAR(); G_LGK0(); G_PRIO1(); MFMA2(0, 1); G_PRIO0(); G_BAR();
    // ph4
    READ_B(0, 1, 2);
    STAGE(0, 0, 1, gAt2 + 32);
    G_BAR(); G_LGK0(); G_PRIO1(); MFMA2(2, 3); G_PRIO0(); G_VM6(); G_BAR();
    // ph5
    READ_A(1, 0); READ_B(1, 0, 0);
    STAGE(0, 1, 1, gBt2 + 32);
    G_BAR(); G_LGK0(); G_PRIO1(); MFMA2(0, 1); G_PRIO0(); G_BAR();
    // ph6
    READ_B(1, 0, 2);
    STAGE(1, 0, 0, gAt3);
    G_BAR(); G_LGK0(); G_PRIO1(); MFMA2(2, 3); G_PRIO0(); G_BAR();
    // ph7
    READ_A(1, 1); READ_B(1, 1, 0);
    STAGE(1, 1, 0, gBt3);
    G_BAR(); G_LGK0(); G_PRIO1(); MFMA2(0, 1); G_PRIO0(); G_BAR();
    // ph8
    READ_B(1, 1, 2);
    STAGE(1, 0, 1, gAt3 + 32);
    G_BAR(); G_LGK0(); G_PRIO1(); MFMA2(2, 3); G_PRIO0(); G_VM6(); G_BAR();
  }

  // final iteration: only ph1 stages (B1 of last tile); drain at ph4
  {
    int t0 = (NI - 1) * 2;
    // ph1
    READ_A(0, 0); READ_B(0, 0, 0);
    STAGE(1, 1, 1, gB + (t0 + 1) * 64 + 32);
    G_BAR(); G_LGK0(); G_PRIO1(); MFMA2(0, 1); G_PRIO0(); G_BAR();
    // ph2
    READ_B(0, 0, 2);
    G_BAR(); G_LGK0(); G_PRIO1(); MFMA2(2, 3); G_PRIO0(); G_BAR();
    // ph3
    READ_A(0, 1); READ_B(0, 1, 0);
    G_BAR(); G_LGK0(); G_PRIO1(); MFMA2(0, 1); G_PRIO0(); G_BAR();
    // ph4
    READ_B(0, 1, 2);
    G_BAR(); G_LGK0(); G_PRIO1(); MFMA2(2, 3); G_PRIO0(); G_VM0(); G_BAR();
    // ph5
    READ_A(1, 0); READ_B(1, 0, 0);
    G_BAR(); G_LGK0(); G_PRIO1(); MFMA2(0, 1); G_PRIO0(); G_BAR();
    // ph6
    READ_B(1, 0, 2);
    G_BAR(); G_LGK0(); G_PRIO1(); MFMA2(2, 3); G_PRIO0(); G_BAR();
    // ph7
    READ_A(1, 1); READ_B(1, 1, 0);
    G_BAR(); G_LGK0(); G_PRIO1(); MFMA2(0, 1); G_PRIO0(); G_BAR();
    // ph8
    READ_B(1, 1, 2);
    G_BAR(); G_LGK0(); G_PRIO1(); MFMA2(2, 3); G_PRIO0();
  }

#pragma unroll
  for (int mt = 0; mt < 8; ++mt)
#pragma unroll
    for (int nt = 0; nt < 4; ++nt)
#pragma unroll
      for (int r = 0; r < 4; ++r) {
        size_t row = (size_t)(m0 + wm * 128 + mt * 16 + quad * 4 + r);
        size_t col = (size_t)(n0 + wn * 64 + nt * 16 + l16);
        Cg[row * Nc + col] = f2bf(acc[mt][nt][r]);
      }
#undef SLAB
#undef STAGE
#undef READ_A
#undef READ_B
#undef MFMA2
}

// ---------------- split-K 128x128 GEMM, fp32 atomic accumulation ------------
__global__ __launch_bounds__(256) void gemm128_splitk_kernel(
    const short* __restrict__ Ag, const short* __restrict__ Btg,
    float* __restrict__ Cfg, int M, int Nc, int K, int KS,
    long sA, long sB, long sC) {
  __shared__ short lds_a[128 * 32];
  __shared__ short lds_b[128 * 32];
  int tid = threadIdx.x;
  int lane = tid & 63;
  int w = tid >> 6;
  int l16 = lane & 15;
  int quad = lane >> 4;
  int wm = w >> 1, wn = w & 1;
  int m0 = blockIdx.x * 128, n0 = blockIdx.y * 128;
  int bz = blockIdx.z / KS;
  int ks = blockIdx.z % KS;
  int kchunk = K / KS;
  int k0 = ks * kchunk;

  const short* A = Ag + (size_t)bz * sA;
  const short* Bt = Btg + (size_t)bz * sB;
  float* Cf = Cfg + (size_t)bz * sC;

  int srow = tid >> 2;
  int skcol = (tid & 3) * 8;
  const short* ag = A + (size_t)(m0 + srow) * K + skcol;
  const short* bg = Bt + (size_t)(n0 + srow) * K + skcol;
  short* la = lds_a + tid * 8;
  short* lb = lds_b + tid * 8;
  const size_t half = (size_t)64 * K;

  floatx4 acc[4][4];
#pragma unroll
  for (int i = 0; i < 4; ++i)
#pragma unroll
    for (int j = 0; j < 4; ++j) acc[i][j] = (floatx4){0.f, 0.f, 0.f, 0.f};

  for (int k = k0; k < k0 + kchunk; k += 32) {
    gld_lds16(ag + k, la);
    gld_lds16(ag + half + k, la + 64 * 32);
    gld_lds16(bg + k, lb);
    gld_lds16(bg + half + k, lb + 64 * 32);
    __syncthreads();

    bf16x8 af[4], bf[4];
#pragma unroll
    for (int mt = 0; mt < 4; ++mt)
      af[mt] = *(const bf16x8*)(lds_a + (wm * 64 + mt * 16 + l16) * 32 + quad * 8);
#pragma unroll
    for (int nt = 0; nt < 4; ++nt)
      bf[nt] = *(const bf16x8*)(lds_b + (wn * 64 + nt * 16 + l16) * 32 + quad * 8);
#pragma unroll
    for (int mt = 0; mt < 4; ++mt)
#pragma unroll
      for (int nt = 0; nt < 4; ++nt)
        acc[mt][nt] = __builtin_amdgcn_mfma_f32_16x16x32_bf16(af[mt], bf[nt], acc[mt][nt], 0, 0, 0);
    __syncthreads();
  }

#pragma unroll
  for (int mt = 0; mt < 4; ++mt)
#pragma unroll
    for (int nt = 0; nt < 4; ++nt)
#pragma unroll
      for (int r = 0; r < 4; ++r) {
        size_t row = (size_t)(m0 + wm * 64 + mt * 16 + quad * 4 + r);
        size_t col = (size_t)(n0 + wn * 64 + nt * 16 + l16);
        atomicAdd(&Cf[row * Nc + col], acc[mt][nt][r]);
      }
}

// ---------------- merged k/v projection GEMM ----------------
__global__ __launch_bounds__(256) void gemm_kv_kernel(
    const short* __restrict__ xp, const short* __restrict__ WkT,
    const short* __restrict__ WvT, short* __restrict__ kpb,
    short* __restrict__ vpT) {
  int tid = threadIdx.x;
  int w = tid >> 6;
  int lane = tid & 63;
  int l16 = lane & 15;
  int quad = lane >> 4;
  int m_base = blockIdx.x * 64 + (w >> 1) * 32;  // E dim
  int n_base = blockIdx.y * 64 + (w & 1) * 32;   // D dim
  int b = blockIdx.z;

  const short* Ab = xp + (size_t)b * E_ * D_;
  short* Ck = kpb + (size_t)b * E_ * D_;
  short* Cv = vpT + (size_t)b * D_ * E_;

  floatx4 acck[2][2], accv[2][2];
#pragma unroll
  for (int i = 0; i < 2; ++i)
#pragma unroll
    for (int j = 0; j < 2; ++j) {
      acck[i][j] = (floatx4){0.f, 0.f, 0.f, 0.f};
      accv[i][j] = (floatx4){0.f, 0.f, 0.f, 0.f};
    }

  for (int k = 0; k < D_; k += 32) {
    bf16x8 a[2], bk[2], bv[2];
#pragma unroll
    for (int mt = 0; mt < 2; ++mt)
      a[mt] = *(const bf16x8*)(Ab + (size_t)(m_base + mt * 16 + l16) * D_ + k + quad * 8);
#pragma unroll
    for (int nt = 0; nt < 2; ++nt) {
      size_t off = (size_t)(n_base + nt * 16 + l16) * D_ + k + quad * 8;
      bk[nt] = *(const bf16x8*)(WkT + off);
      bv[nt] = *(const bf16x8*)(WvT + off);
    }
#pragma unroll
    for (int mt = 0; mt < 2; ++mt)
#pragma unroll
      for (int nt = 0; nt < 2; ++nt) {
        acck[mt][nt] = __builtin_amdgcn_mfma_f32_16x16x32_bf16(a[mt], bk[nt], acck[mt][nt], 0, 0, 0);
        accv[mt][nt] = __builtin_amdgcn_mfma_f32_16x16x32_bf16(a[mt], bv[nt], accv[mt][nt], 0, 0, 0);
      }
  }

#pragma unroll
  for (int mt = 0; mt < 2; ++mt)
#pragma unroll
    for (int nt = 0; nt < 2; ++nt)
#pragma unroll
      for (int r = 0; r < 4; ++r) {
        size_t row = (size_t)(m_base + mt * 16 + quad * 4 + r);  // E index
        size_t col = (size_t)(n_base + nt * 16 + l16);           // D index
        Ck[row * D_ + col] = f2bf(acck[mt][nt][r]);
        Cv[col * E_ + row] = f2bf(accv[mt][nt][r]);
      }
}

// ---------------- fused attention v3 (unchanged) ----------------
__global__ __launch_bounds__(512) void attn_kernel(
    const short* __restrict__ q,    // [B*N, D] bf16
    const short* __restrict__ kp,   // [B, E, D] bf16
    const short* __restrict__ vpT,  // [B, D, E] bf16
    float* __restrict__ out) {      // [B, N, D] fp32
  __shared__ short lds_kp_p[17408];  // kp tile (32768 B) then P (34816 B)
  __shared__ short lds_vp[16384];    // vpT tile

  int tid = threadIdx.x;
  int w = tid >> 6;
  int lane = tid & 63;
  int l16 = lane & 15;
  int quad = lane >> 4;
  int n0 = blockIdx.x * 128;
  int h = blockIdx.y;
  int b = blockIdx.z;

  {
    const short* kpg = kp + (size_t)b * E_ * D_ + h * 64;
    int r0 = tid >> 3;
    int sseg = (tid & 7) ^ (r0 & 7);
#pragma unroll
    for (int j = 0; j < 4; ++j)
      gld_lds16(kpg + (size_t)(r0 + j * 64) * D_ + sseg * 8,
                lds_kp_p + j * 4096 + tid * 8);
  }
  {
    const short* vpg = vpT + (size_t)b * D_ * E_ + (size_t)(h * 64) * E_;
    int s1 = tid & 31;
    int rb = tid >> 5;
    int sseg = (s1 & 24) | ((s1 & 7) ^ (rb & 7));
#pragma unroll
    for (int j = 0; j < 4; ++j)
      gld_lds16(vpg + (size_t)(rb + j * 16) * E_ + sseg * 8,
                lds_vp + j * 4096 + tid * 8);
  }

  const short* qbase = q + ((size_t)(b * N_ + n0 + w * 16 + l16)) * D_ + h * 64;
  bf16x8 qf0 = *(const bf16x8*)(qbase + quad * 8);
  bf16x8 qf1 = *(const bf16x8*)(qbase + 32 + quad * 8);

  __syncthreads();

  floatx4 s[16];
#pragma unroll
  for (int t = 0; t < 16; ++t) s[t] = (floatx4){0.f, 0.f, 0.f, 0.f};

  int sw = l16 & 7;
#pragma unroll
  for (int t = 0; t < 16; ++t) {
    int r = t * 16 + l16;
    const short* rowp = lds_kp_p + r * 64;
    bf16x8 a0 = *(const bf16x8*)(rowp + ((quad) ^ sw) * 8);
    bf16x8 a1 = *(const bf16x8*)(rowp + ((4 + quad) ^ sw) * 8);
    s[t] = __builtin_amdgcn_mfma_f32_16x16x32_bf16(a0, qf0, s[t], 0, 0, 0);
    s[t] = __builtin_amdgcn_mfma_f32_16x16x32_bf16(a1, qf1, s[t], 0, 0, 0);
  }

  float mx = -1e30f;
#pragma unroll
  for (int t = 0; t < 16; ++t)
#pragma unroll
    for (int r = 0; r < 4; ++r) {
      s[t][r] *= 0.125f;
      mx = fmaxf(mx, s[t][r]);
    }
  mx = fmaxf(mx, __shfl_xor(mx, 16, 64));
  mx = fmaxf(mx, __shfl_xor(mx, 32, 64));

  float lsum = 0.f;
#pragma unroll
  for (int t = 0; t < 16; ++t)
#pragma unroll
    for (int r = 0; r < 4; ++r) {
      s[t][r] = __expf(s[t][r] - mx);
      lsum += s[t][r];
    }
  lsum += __shfl_xor(lsum, 16, 64);
  lsum += __shfl_xor(lsum, 32, 64);

  __syncthreads();

  short* pbase = lds_kp_p + w * 2176;
  floatx4 o4[4];
#pragma unroll
  for (int t2 = 0; t2 < 4; ++t2) o4[t2] = (floatx4){0.f, 0.f, 0.f, 0.f};

#pragma unroll
  for (int hf = 0; hf < 2; ++hf) {
#pragma unroll
    for (int t = 0; t < 8; ++t)
#pragma unroll
      for (int r = 0; r < 4; ++r)
        pbase[l16 * 136 + t * 16 + quad * 4 + r] = f2bf(s[hf * 8 + t][r]);

#pragma unroll
    for (int es2 = 0; es2 < 4; ++es2) {
      bf16x8 pa = *(const bf16x8*)(pbase + l16 * 136 + es2 * 32 + quad * 8);
      int es = hf * 4 + es2;
#pragma unroll
      for (int t2 = 0; t2 < 4; ++t2) {
        int rr = t2 * 16 + l16;
        int seg = es * 4 + quad;
        int sg = (seg & 24) | ((seg & 7) ^ sw);
        bf16x8 vf = *(const bf16x8*)(lds_vp + rr * 256 + sg * 8);
        o4[t2] = __builtin_amdgcn_mfma_f32_16x16x32_bf16(pa, vf, o4[t2], 0, 0, 0);
      }
    }
  }

  float linv[4];
#pragma unroll
  for (int r = 0; r < 4; ++r)
    linv[r] = 1.0f / __shfl(lsum, (lane & 48) | (quad * 4 + r), 64);

#pragma unroll
  for (int r = 0; r < 4; ++r) {
    int n = n0 + w * 16 + quad * 4 + r;
#pragma unroll
    for (int t2 = 0; t2 < 4; ++t2)
      out[((size_t)(b * N_ + n)) * D_ + h * 64 + t2 * 16 + l16] = o4[t2][r] * linv[r];
  }
}

extern "C" void kernel_launch(void* const* d_in, const int* in_sizes, int n_in,
                              void* d_out, int out_size, void* d_ws, size_t ws_size,
                              hipStream_t stream) {
  const float* x    = (const float*)d_in[0];  // [B,N,D]
  const float* proj = (const float*)d_in[1];  // [N,E]
  const float* Wq   = (const float*)d_in[2];  // [D,D]
  const float* Wk   = (const float*)d_in[3];
  const float* Wv   = (const float*)d_in[4];
  float* out = (float*)d_out;

  short* p = (short*)d_ws;
  short* xtb_qb = p; p += (size_t)B_ * D_ * N_;  // xtb, later qb
  short* xb     = p; p += (size_t)B_ * N_ * D_;
  short* WqT    = p; p += (size_t)D_ * D_;
  short* WkT    = p; p += (size_t)D_ * D_;
  short* WvT    = p; p += (size_t)D_ * D_;
  short* projT  = p; p += (size_t)E_ * N_;
  short* xp     = p; p += (size_t)B_ * E_ * D_;
  short* kpb    = p; p += (size_t)B_ * E_ * D_;
  short* vpT    = p; p += (size_t)B_ * D_ * E_;
  float* xp_f32 = (float*)p;                     // B*E*D fp32 = 4 MB
  short* xtb = xtb_qb;
  short* qb  = xtb_qb;

  dim3 blkT(32, 8);
  transpose_x_kernel<<<dim3(D_ / 32, N_ / 32, B_), blkT, 0, stream>>>(x, xtb, xb);
  transpose_w_kernel<<<dim3(D_ / 32, D_ / 32, 3), blkT, 0, stream>>>(Wq, Wk, Wv, WqT, WkT, WvT);
  transpose_p_kernel<<<dim3(E_ / 32, N_ / 32, 1), blkT, 0, stream>>>(proj, projT);

  // xp[b] = proj^T @ x[b] — split-K (KS=8 -> 512 blocks) + fp32 atomics
  hipMemsetAsync(xp_f32, 0, (size_t)B_ * E_ * D_ * sizeof(float), stream);
  const int KS = 8;
  gemm128_splitk_kernel<<<dim3(E_ / 128, D_ / 128, B_ * KS), 256, 0, stream>>>(
      projT, xtb, xp_f32, E_, D_, N_, KS, 0, (long)D_ * N_, (long)E_ * D_);
  cast_f32_bf16_kernel<<<(B_ * E_ * D_) / 1024, 256, 0, stream>>>(xp_f32, xp);

  // q = xb @ W_q — 256^2 8-phase kernel (qb overwrites dead xtb)
  gemm256_bt_kernel<<<dim3(((B_ * N_) / 256) * (D_ / 256)), 512, 0, stream>>>(
      xb, WqT, qb, B_ * N_, D_, D_);

  // k_proj / v_proj^T fused (shared A-fragments)
  gemm_kv_kernel<<<dim3(E_ / 64, D_ / 64, B_), 256, 0, stream>>>(
      xp, WkT, WvT, kpb, vpT);

  attn_kernel<<<dim3(N_ / 128, H_, B_), 512, 0, stream>>>(qb, kpb, vpT, out);
}

// Round 2
// 253.395 us; speedup vs baseline: 1.1927x; 1.1269x over previous
//
#include <hip/hip_runtime.h>
#include <hip/hip_bf16.h>

#define B_ 4
#define N_ 4096
#define D_ 1024
#define H_ 16
#define E_ 256
#define HD_ 64

typedef __attribute__((ext_vector_type(8))) short bf16x8;
typedef __attribute__((ext_vector_type(4))) short shortx4;
typedef __attribute__((ext_vector_type(4))) float floatx4;

__device__ inline short f2bf(float f) {
  __hip_bfloat16 h = __float2bfloat16(f);
  short s;
  __builtin_memcpy(&s, &h, 2);
  return s;
}

// async global->LDS, 16 bytes per lane (dest = wave-uniform base + lane*16)
__device__ inline void gld_lds16(const short* g, short* l) {
  __builtin_amdgcn_global_load_lds(
      (const __attribute__((address_space(1))) void*)g,
      (__attribute__((address_space(3))) void*)l, 16, 0, 0);
}

#define G_BAR() __builtin_amdgcn_s_barrier()
#define G_LGK0() asm volatile("s_waitcnt lgkmcnt(0)" ::: "memory")
#define G_VM0() asm volatile("s_waitcnt vmcnt(0)" ::: "memory")
#define G_VM4() asm volatile("s_waitcnt vmcnt(4)" ::: "memory")
#define G_VM6() asm volatile("s_waitcnt vmcnt(6)" ::: "memory")
#define G_VM8() asm volatile("s_waitcnt vmcnt(8)" ::: "memory")
#define G_VM12() asm volatile("s_waitcnt vmcnt(12)" ::: "memory")
#define G_PRIO1() __builtin_amdgcn_s_setprio(1)
#define G_PRIO0() __builtin_amdgcn_s_setprio(0)

// ---------------- transpose + cast fp32 -> bf16 (shared body) ----------------
template <bool CAST_COPY>
__device__ inline void transpose_body(const float* __restrict__ src,
                                      short* __restrict__ dstT,
                                      short* __restrict__ dstC,
                                      int R, int C) {
  __shared__ float tile[32][33];
  int c0 = blockIdx.x * 32;
  int r0 = blockIdx.y * 32;
  int tx = threadIdx.x;   // 0..31
  int ty = threadIdx.y;   // 0..7
#pragma unroll
  for (int i = 0; i < 4; ++i) {
    int r = ty * 4 + i;
    float v = src[(size_t)(r0 + r) * C + (c0 + tx)];
    tile[r][tx] = v;
    if constexpr (CAST_COPY)
      dstC[(size_t)(r0 + r) * C + (c0 + tx)] = f2bf(v);
  }
  __syncthreads();
#pragma unroll
  for (int i = 0; i < 4; ++i) {
    int c = ty * 4 + i;
    dstT[(size_t)(c0 + c) * R + (r0 + tx)] = f2bf(tile[tx][c]);
  }
}

__global__ void transpose_x_kernel(const float* __restrict__ x,
                                   short* __restrict__ xtb,
                                   short* __restrict__ xb) {
  int b = blockIdx.z;
  transpose_body<true>(x + (size_t)b * N_ * D_, xtb + (size_t)b * D_ * N_,
                       xb + (size_t)b * N_ * D_, N_, D_);
}

__global__ void transpose_w_kernel(const float* __restrict__ Wq,
                                   const float* __restrict__ Wk,
                                   const float* __restrict__ Wv,
                                   short* __restrict__ WqT,
                                   short* __restrict__ WkT,
                                   short* __restrict__ WvT) {
  int z = blockIdx.z;
  const float* src = (z == 0) ? Wq : (z == 1) ? Wk : Wv;
  short* dst = (z == 0) ? WqT : (z == 1) ? WkT : WvT;
  transpose_body<false>(src, dst, nullptr, D_, D_);
}

__global__ void transpose_p_kernel(const float* __restrict__ proj,
                                   short* __restrict__ projT) {
  transpose_body<false>(proj, projT, nullptr, N_, E_);
}

// ===========================================================================
// xp kernel: xp[b] = projT[E,N] @ xtb[b][D,N]^T  -> [E, D] bf16, single pass.
// 256 blocks = 4 E-tiles x 16 D-tiles x 4 batches, 256 thr = 4 waves (2x2
// sub-tiles of 32x32), full K = 4096, NO split-K / atomics.
// 4-deep pipeline: prologue stages tiles 0..3 (16 loads in flight); each
// iter waits vmcnt(12) (counted, never 0 in steady state), reads swizzled
// frags, lgkmcnt(0)+barrier, re-stages tile t+4 into the just-consumed buf,
// then MFMAs. Tail peels 3 iters at vmcnt(8)/(4)/(0).
// LDS: 4 buf x {A,B} x [64 rows][64 cols bf16] (8 KiB slabs) = 64 KiB.
// Swizzle: byte a ^= ((a>>7)&7)<<4 on BOTH pre-swizzled global src and reads.
// XCD grouping: the 4 E-tile blocks sharing a B-slab land on one XCD.
// ===========================================================================
__device__ inline bf16x8 fragx(const short* slab, int row, int q) {
  int a = (row << 7) + (q << 4);
  a ^= ((a >> 7) & 7) << 4;
  return *(const bf16x8*)(slab + (a >> 1));
}

__global__ __launch_bounds__(256) void xp_kernel(
    const short* __restrict__ projT, const short* __restrict__ xtb,
    short* __restrict__ xp) {
  __shared__ short lds[32768];  // 64 KiB: 8 slabs of 4096 shorts
#define XSLAB(bu, o) (lds + (((bu) << 1) | (o)) * 4096)

  int tid = threadIdx.x;
  int lane = tid & 63;
  int w = tid >> 6;
  int l16 = lane & 15;
  int quad = lane >> 4;
  int wm = w >> 1, wn = w & 1;

  // bid = ((g>>3)*4 + et)*8 + (g&7): group g=(b,dt) pinned to one XCD with
  // its 4 E-tile blocks adjacent -> B-slab L2 reuse.
  int bid = blockIdx.x;
  int xcd = bid & 7;
  int slot = bid >> 3;
  int et = slot & 3;
  int grp = (slot >> 2) * 8 + xcd;
  int b = grp >> 4;
  int dt = grp & 15;
  int e0 = et * 64, d0 = dt * 64;

  const short* Abase = projT + (size_t)e0 * N_;
  const short* Bbase = xtb + (size_t)b * D_ * N_ + (size_t)d0 * N_;

  // pre-swizzled global source offsets for the two 16B chunks per slab
  int p0 = tid * 16;
  int w0s = p0 ^ (((p0 >> 7) & 7) << 4);
  int p1 = p0 + 4096;
  int w1s = p1 ^ (((p1 >> 7) & 7) << 4);
  size_t so0 = (size_t)(w0s >> 7) * N_ + ((w0s & 127) >> 1);
  size_t so1 = (size_t)(w1s >> 7) * N_ + ((w1s & 127) >> 1);

#define XSTAGE(bu, k)                                      \
  do {                                                     \
    short* _la = XSLAB(bu, 0);                             \
    short* _lb = XSLAB(bu, 1);                             \
    gld_lds16(Abase + (k) + so0, _la + tid * 8);           \
    gld_lds16(Abase + (k) + so1, _la + 2048 + tid * 8);    \
    gld_lds16(Bbase + (k) + so0, _lb + tid * 8);           \
    gld_lds16(Bbase + (k) + so1, _lb + 2048 + tid * 8);    \
  } while (0)

  floatx4 acc[2][2];
#pragma unroll
  for (int i = 0; i < 2; ++i)
#pragma unroll
    for (int j = 0; j < 2; ++j) acc[i][j] = (floatx4){0.f, 0.f, 0.f, 0.f};

  bf16x8 afr[2][2], bfr[2][2];

#define XREAD(bu)                                                          \
  do {                                                                     \
    const short* _sa = XSLAB(bu, 0);                                       \
    const short* _sb = XSLAB(bu, 1);                                       \
    _Pragma("unroll") for (int kk = 0; kk < 2; ++kk) {                     \
      _Pragma("unroll") for (int mt = 0; mt < 2; ++mt)                     \
          afr[kk][mt] = fragx(_sa, wm * 32 + mt * 16 + l16, kk * 4 + quad);\
      _Pragma("unroll") for (int nt = 0; nt < 2; ++nt)                     \
          bfr[kk][nt] = fragx(_sb, wn * 32 + nt * 16 + l16, kk * 4 + quad);\
    }                                                                      \
  } while (0)

#define XMFMA()                                                            \
  do {                                                                     \
    _Pragma("unroll") for (int kk = 0; kk < 2; ++kk)                       \
      _Pragma("unroll") for (int mt = 0; mt < 2; ++mt)                     \
        _Pragma("unroll") for (int nt = 0; nt < 2; ++nt)                   \
            acc[mt][nt] = __builtin_amdgcn_mfma_f32_16x16x32_bf16(         \
                afr[kk][mt], bfr[kk][nt], acc[mt][nt], 0, 0, 0);           \
  } while (0)

  // prologue: 4 K-tiles in flight (16 loads)
  XSTAGE(0, 0);
  XSTAGE(1, 64);
  XSTAGE(2, 128);
  XSTAGE(3, 192);

#pragma unroll 1
  for (int t = 0; t < (N_ / 64) - 4; ++t) {
    G_VM12();            // tile t complete (12 newer loads may stay in flight)
    G_BAR();
    XREAD(t & 3);
    G_LGK0();            // my frag reads landed
    G_BAR();             // everyone's frag reads landed -> safe to overwrite
    XSTAGE(t & 3, (t + 4) * 64);
    G_PRIO1(); XMFMA(); G_PRIO0();
  }
  // tail: tiles 60..63, no more staging; counted drain 12 -> 8 -> 4 -> 0
  G_VM12(); G_BAR(); XREAD(0); G_LGK0(); G_PRIO1(); XMFMA(); G_PRIO0();
  G_VM8();  G_BAR(); XREAD(1); G_LGK0(); G_PRIO1(); XMFMA(); G_PRIO0();
  G_VM4();  G_BAR(); XREAD(2); G_LGK0(); G_PRIO1(); XMFMA(); G_PRIO0();
  G_VM0();  G_BAR(); XREAD(3); G_LGK0(); G_PRIO1(); XMFMA(); G_PRIO0();

  short* C = xp + (size_t)b * E_ * D_;
#pragma unroll
  for (int mt = 0; mt < 2; ++mt)
#pragma unroll
    for (int nt = 0; nt < 2; ++nt)
#pragma unroll
      for (int r = 0; r < 4; ++r) {
        size_t row = (size_t)(e0 + wm * 32 + mt * 16 + quad * 4 + r);
        size_t col = (size_t)(d0 + wn * 32 + nt * 16 + l16);
        C[row * D_ + col] = f2bf(acc[mt][nt][r]);
      }
#undef XSLAB
#undef XSTAGE
#undef XREAD
#undef XMFMA
}

// ===========================================================================
// 256x256 8-phase bf16 GEMM (T1+T2+T3+T4+T5), C[M,Nc] = A[M,K] * Bt[Nc,K]^T
// (unchanged from round 0 — see comments there)
// ===========================================================================
__device__ inline bf16x8 frag256(const short* slab, int row, int q) {
  int a = (row << 6) + (q << 4);
  a ^= ((a >> 7) & 7) << 4;
  return *(const bf16x8*)(slab + (a >> 1));
}

__global__ __launch_bounds__(512) void gemm256_bt_kernel(
    const short* __restrict__ Ag, const short* __restrict__ Btg,
    short* __restrict__ Cg, int M, int Nc, int K) {
  __shared__ short lds[65536];  // 128 KiB: 8 slabs of 8192 shorts
#define SLAB(b, o, kk2) (lds + ((((((b) << 1) | (o)) << 1) | (kk2)) * 8192))

  int tid = threadIdx.x;
  int lane = tid & 63;
  int w = tid >> 6;
  int l16 = lane & 15;
  int quad = lane >> 4;
  int wm = w >> 2;   // 0..1
  int wn = w & 3;    // 0..3

  // XCD-bijective swizzle (gridDim.x % 8 == 0 here: 256 blocks)
  int nwg = gridDim.x;
  int cpx = nwg >> 3;
  int bid = blockIdx.x;
  int swz = (bid & 7) * cpx + (bid >> 3);
  int ntile_m = M >> 8;
  int tm = swz % ntile_m;
  int tn = swz / ntile_m;
  int m0 = tm * 256, n0 = tn * 256;

  const short* gA = Ag + (size_t)m0 * K;
  const short* gB = Btg + (size_t)n0 * K;

  // pre-swizzled staging source offsets (shared by A and B; same ld = K)
  int a0 = tid * 16;
  int w0 = a0 ^ (((a0 >> 7) & 7) << 4);
  int a1 = (tid + 512) * 16;
  int w1 = a1 ^ (((a1 >> 7) & 7) << 4);
  size_t so0 = (size_t)(w0 >> 6) * K + ((w0 & 63) >> 1);
  size_t so1 = (size_t)(w1 >> 6) * K + ((w1 & 63) >> 1);

#define STAGE(b, o, kk2, gsrc)                      \
  do {                                              \
    short* _sl = SLAB(b, o, kk2);                   \
    gld_lds16((gsrc) + so0, _sl + tid * 8);         \
    gld_lds16((gsrc) + so1, _sl + 4096 + tid * 8);  \
  } while (0)

  floatx4 acc[8][4];
#pragma unroll
  for (int i = 0; i < 8; ++i)
#pragma unroll
    for (int j = 0; j < 4; ++j) acc[i][j] = (floatx4){0.f, 0.f, 0.f, 0.f};

  bf16x8 af[8], bfr0, bfr1;

#define READ_A(bu, kk2)                                             \
  do {                                                              \
    const short* _sa = SLAB(bu, 0, kk2);                            \
    _Pragma("unroll") for (int mt = 0; mt < 8; ++mt)                \
        af[mt] = frag256(_sa, wm * 128 + mt * 16 + l16, quad);      \
  } while (0)
#define READ_B(bu, kk2, ntb)                                        \
  do {                                                              \
    const short* _sb = SLAB(bu, 1, kk2);                            \
    bfr0 = frag256(_sb, wn * 64 + (ntb)*16 + l16, quad);            \
    bfr1 = frag256(_sb, wn * 64 + (ntb)*16 + 16 + l16, quad);       \
  } while (0)
#define MFMA2(c0, c1)                                                          \
  do {                                                                         \
    _Pragma("unroll") for (int mt = 0; mt < 8; ++mt) {                         \
      acc[mt][c0] =                                                            \
          __builtin_amdgcn_mfma_f32_16x16x32_bf16(af[mt], bfr0, acc[mt][c0],   \
                                                  0, 0, 0);                    \
      acc[mt][c1] =                                                            \
          __builtin_amdgcn_mfma_f32_16x16x32_bf16(af[mt], bfr1, acc[mt][c1],   \
                                                  0, 0, 0);                    \
    }                                                                          \
  } while (0)

  // prologue: tile0 (4 halves) + tile1 (A0,B0,A1); keep newest 3 in flight
  STAGE(0, 0, 0, gA);
  STAGE(0, 1, 0, gB);
  STAGE(0, 0, 1, gA + 32);
  STAGE(0, 1, 1, gB + 32);
  STAGE(1, 0, 0, gA + 64);
  STAGE(1, 1, 0, gB + 64);
  STAGE(1, 0, 1, gA + 96);
  G_VM6();
  G_BAR();

  const int NI = K >> 7;  // iterations of 2 K-tiles
#pragma unroll 1
  for (int it = 0; it < NI - 1; ++it) {
    int t0 = it * 2;
    const short* gAt2 = gA + (t0 + 2) * 64;
    const short* gBt2 = gB + (t0 + 2) * 64;
    const short* gAt3 = gA + (t0 + 3) * 64;
    const short* gBt3 = gB + (t0 + 3) * 64;
    // ph1
    READ_A(0, 0); READ_B(0, 0, 0);
    STAGE(1, 1, 1, gB + (t0 + 1) * 64 + 32);
    G_BAR(); G_LGK0(); G_PRIO1(); MFMA2(0, 1); G_PRIO0(); G_BAR();
    // ph2
    READ_B(0, 0, 2);
    STAGE(0, 0, 0, gAt2);
    G_BAR(); G_LGK0(); G_PRIO1(); MFMA2(2, 3); G_PRIO0(); G_BAR();
    // ph3
    READ_A(0, 1); READ_B(0, 1, 0);
    STAGE(0, 1, 0, gBt2);
    G_BAR(); G_LGK0(); G_PRIO1(); MFMA2(0, 1); G_PRIO0(); G_BAR();
    // ph4
    READ_B(0, 1, 2);
    STAGE(0, 0, 1, gAt2 + 32);
    G_BAR(); G_LGK0(); G_PRIO1(); MFMA2(2, 3); G_PRIO0(); G_VM6(); G_BAR();
    // ph5
    READ_A(1, 0); READ_B(1, 0, 0);
    STAGE(0, 1, 1, gBt2 + 32);
    G_BAR(); G_LGK0(); G_PRIO1(); MFMA2(0, 1); G_PRIO0(); G_BAR();
    // ph6
    READ_B(1, 0, 2);
    STAGE(1, 0, 0, gAt3);
    G_BAR(); G_LGK0(); G_PRIO1(); MFMA2(2, 3); G_PRIO0(); G_BAR();
    // ph7
    READ_A(1, 1); READ_B(1, 1, 0);
    STAGE(1, 1, 0, gBt3);
    G_BAR(); G_LGK0(); G_PRIO1(); MFMA2(0, 1); G_PRIO0(); G_BAR();
    // ph8
    READ_B(1, 1, 2);
    STAGE(1, 0, 1, gAt3 + 32);
    G_BAR(); G_LGK0(); G_PRIO1(); MFMA2(2, 3); G_PRIO0(); G_VM6(); G_BAR();
  }

  // final iteration: only ph1 stages (B1 of last tile); drain at ph4
  {
    int t0 = (NI - 1) * 2;
    // ph1
    READ_A(0, 0); READ_B(0, 0, 0);
    STAGE(1, 1, 1, gB + (t0 + 1) * 64 + 32);
    G_BAR(); G_LGK0(); G_PRIO1(); MFMA2(0, 1); G_PRIO0(); G_BAR();
    // ph2
    READ_B(0, 0, 2);
    G_BAR(); G_LGK0(); G_PRIO1(); MFMA2(2, 3); G_PRIO0(); G_BAR();
    // ph3
    READ_A(0, 1); READ_B(0, 1, 0);
    G_BAR(); G_LGK0(); G_PRIO1(); MFMA2(0, 1); G_PRIO0(); G_BAR();
    // ph4
    READ_B(0, 1, 2);
    G_BAR(); G_LGK0(); G_PRIO1(); MFMA2(2, 3); G_PRIO0(); G_VM0(); G_BAR();
    // ph5
    READ_A(1, 0); READ_B(1, 0, 0);
    G_BAR(); G_LGK0(); G_PRIO1(); MFMA2(0, 1); G_PRIO0(); G_BAR();
    // ph6
    READ_B(1, 0, 2);
    G_BAR(); G_LGK0(); G_PRIO1(); MFMA2(2, 3); G_PRIO0(); G_BAR();
    // ph7
    READ_A(1, 1); READ_B(1, 1, 0);
    G_BAR(); G_LGK0(); G_PRIO1(); MFMA2(0, 1); G_PRIO0(); G_BAR();
    // ph8
    READ_B(1, 1, 2);
    G_BAR(); G_LGK0(); G_PRIO1(); MFMA2(2, 3); G_PRIO0();
  }

#pragma unroll
  for (int mt = 0; mt < 8; ++mt)
#pragma unroll
    for (int nt = 0; nt < 4; ++nt)
#pragma unroll
      for (int r = 0; r < 4; ++r) {
        size_t row = (size_t)(m0 + wm * 128 + mt * 16 + quad * 4 + r);
        size_t col = (size_t)(n0 + wn * 64 + nt * 16 + l16);
        Cg[row * Nc + col] = f2bf(acc[mt][nt][r]);
      }
#undef SLAB
#undef STAGE
#undef READ_A
#undef READ_B
#undef MFMA2
}

// ---------------- merged k/v projection GEMM ----------------
__global__ __launch_bounds__(256) void gemm_kv_kernel(
    const short* __restrict__ xp, const short* __restrict__ WkT,
    const short* __restrict__ WvT, short* __restrict__ kpb,
    short* __restrict__ vpT) {
  int tid = threadIdx.x;
  int w = tid >> 6;
  int lane = tid & 63;
  int l16 = lane & 15;
  int quad = lane >> 4;
  int m_base = blockIdx.x * 64 + (w >> 1) * 32;  // E dim
  int n_base = blockIdx.y * 64 + (w & 1) * 32;   // D dim
  int b = blockIdx.z;

  const short* Ab = xp + (size_t)b * E_ * D_;
  short* Ck = kpb + (size_t)b * E_ * D_;
  short* Cv = vpT + (size_t)b * D_ * E_;

  floatx4 acck[2][2], accv[2][2];
#pragma unroll
  for (int i = 0; i < 2; ++i)
#pragma unroll
    for (int j = 0; j < 2; ++j) {
      acck[i][j] = (floatx4){0.f, 0.f, 0.f, 0.f};
      accv[i][j] = (floatx4){0.f, 0.f, 0.f, 0.f};
    }

  for (int k = 0; k < D_; k += 32) {
    bf16x8 a[2], bk[2], bv[2];
#pragma unroll
    for (int mt = 0; mt < 2; ++mt)
      a[mt] = *(const bf16x8*)(Ab + (size_t)(m_base + mt * 16 + l16) * D_ + k + quad * 8);
#pragma unroll
    for (int nt = 0; nt < 2; ++nt) {
      size_t off = (size_t)(n_base + nt * 16 + l16) * D_ + k + quad * 8;
      bk[nt] = *(const bf16x8*)(WkT + off);
      bv[nt] = *(const bf16x8*)(WvT + off);
    }
#pragma unroll
    for (int mt = 0; mt < 2; ++mt)
#pragma unroll
      for (int nt = 0; nt < 2; ++nt) {
        acck[mt][nt] = __builtin_amdgcn_mfma_f32_16x16x32_bf16(a[mt], bk[nt], acck[mt][nt], 0, 0, 0);
        accv[mt][nt] = __builtin_amdgcn_mfma_f32_16x16x32_bf16(a[mt], bv[nt], accv[mt][nt], 0, 0, 0);
      }
  }

#pragma unroll
  for (int mt = 0; mt < 2; ++mt)
#pragma unroll
    for (int nt = 0; nt < 2; ++nt)
#pragma unroll
      for (int r = 0; r < 4; ++r) {
        size_t row = (size_t)(m_base + mt * 16 + quad * 4 + r);  // E index
        size_t col = (size_t)(n_base + nt * 16 + l16);           // D index
        Ck[row * D_ + col] = f2bf(acck[mt][nt][r]);
        Cv[col * E_ + row] = f2bf(accv[mt][nt][r]);
      }
}

// ---------------- fused attention v3 (unchanged) ----------------
__global__ __launch_bounds__(512) void attn_kernel(
    const short* __restrict__ q,    // [B*N, D] bf16
    const short* __restrict__ kp,   // [B, E, D] bf16
    const short* __restrict__ vpT,  // [B, D, E] bf16
    float* __restrict__ out) {      // [B, N, D] fp32
  __shared__ short lds_kp_p[17408];  // kp tile (32768 B) then P (34816 B)
  __shared__ short lds_vp[16384];    // vpT tile

  int tid = threadIdx.x;
  int w = tid >> 6;
  int lane = tid & 63;
  int l16 = lane & 15;
  int quad = lane >> 4;
  int n0 = blockIdx.x * 128;
  int h = blockIdx.y;
  int b = blockIdx.z;

  {
    const short* kpg = kp + (size_t)b * E_ * D_ + h * 64;
    int r0 = tid >> 3;
    int sseg = (tid & 7) ^ (r0 & 7);
#pragma unroll
    for (int j = 0; j < 4; ++j)
      gld_lds16(kpg + (size_t)(r0 + j * 64) * D_ + sseg * 8,
                lds_kp_p + j * 4096 + tid * 8);
  }
  {
    const short* vpg = vpT + (size_t)b * D_ * E_ + (size_t)(h * 64) * E_;
    int s1 = tid & 31;
    int rb = tid >> 5;
    int sseg = (s1 & 24) | ((s1 & 7) ^ (rb & 7));
#pragma unroll
    for (int j = 0; j < 4; ++j)
      gld_lds16(vpg + (size_t)(rb + j * 16) * E_ + sseg * 8,
                lds_vp + j * 4096 + tid * 8);
  }

  const short* qbase = q + ((size_t)(b * N_ + n0 + w * 16 + l16)) * D_ + h * 64;
  bf16x8 qf0 = *(const bf16x8*)(qbase + quad * 8);
  bf16x8 qf1 = *(const bf16x8*)(qbase + 32 + quad * 8);

  __syncthreads();

  floatx4 s[16];
#pragma unroll
  for (int t = 0; t < 16; ++t) s[t] = (floatx4){0.f, 0.f, 0.f, 0.f};

  int sw = l16 & 7;
#pragma unroll
  for (int t = 0; t < 16; ++t) {
    int r = t * 16 + l16;
    const short* rowp = lds_kp_p + r * 64;
    bf16x8 a0 = *(const bf16x8*)(rowp + ((quad) ^ sw) * 8);
    bf16x8 a1 = *(const bf16x8*)(rowp + ((4 + quad) ^ sw) * 8);
    s[t] = __builtin_amdgcn_mfma_f32_16x16x32_bf16(a0, qf0, s[t], 0, 0, 0);
    s[t] = __builtin_amdgcn_mfma_f32_16x16x32_bf16(a1, qf1, s[t], 0, 0, 0);
  }

  float mx = -1e30f;
#pragma unroll
  for (int t = 0; t < 16; ++t)
#pragma unroll
    for (int r = 0; r < 4; ++r) {
      s[t][r] *= 0.125f;
      mx = fmaxf(mx, s[t][r]);
    }
  mx = fmaxf(mx, __shfl_xor(mx, 16, 64));
  mx = fmaxf(mx, __shfl_xor(mx, 32, 64));

  float lsum = 0.f;
#pragma unroll
  for (int t = 0; t < 16; ++t)
#pragma unroll
    for (int r = 0; r < 4; ++r) {
      s[t][r] = __expf(s[t][r] - mx);
      lsum += s[t][r];
    }
  lsum += __shfl_xor(lsum, 16, 64);
  lsum += __shfl_xor(lsum, 32, 64);

  __syncthreads();

  short* pbase = lds_kp_p + w * 2176;
  floatx4 o4[4];
#pragma unroll
  for (int t2 = 0; t2 < 4; ++t2) o4[t2] = (floatx4){0.f, 0.f, 0.f, 0.f};

#pragma unroll
  for (int hf = 0; hf < 2; ++hf) {
#pragma unroll
    for (int t = 0; t < 8; ++t)
#pragma unroll
      for (int r = 0; r < 4; ++r)
        pbase[l16 * 136 + t * 16 + quad * 4 + r] = f2bf(s[hf * 8 + t][r]);

#pragma unroll
    for (int es2 = 0; es2 < 4; ++es2) {
      bf16x8 pa = *(const bf16x8*)(pbase + l16 * 136 + es2 * 32 + quad * 8);
      int es = hf * 4 + es2;
#pragma unroll
      for (int t2 = 0; t2 < 4; ++t2) {
        int rr = t2 * 16 + l16;
        int seg = es * 4 + quad;
        int sg = (seg & 24) | ((seg & 7) ^ sw);
        bf16x8 vf = *(const bf16x8*)(lds_vp + rr * 256 + sg * 8);
        o4[t2] = __builtin_amdgcn_mfma_f32_16x16x32_bf16(pa, vf, o4[t2], 0, 0, 0);
      }
    }
  }

  float linv[4];
#pragma unroll
  for (int r = 0; r < 4; ++r)
    linv[r] = 1.0f / __shfl(lsum, (lane & 48) | (quad * 4 + r), 64);

#pragma unroll
  for (int r = 0; r < 4; ++r) {
    int n = n0 + w * 16 + quad * 4 + r;
#pragma unroll
    for (int t2 = 0; t2 < 4; ++t2)
      out[((size_t)(b * N_ + n)) * D_ + h * 64 + t2 * 16 + l16] = o4[t2][r] * linv[r];
  }
}

extern "C" void kernel_launch(void* const* d_in, const int* in_sizes, int n_in,
                              void* d_out, int out_size, void* d_ws, size_t ws_size,
                              hipStream_t stream) {
  const float* x    = (const float*)d_in[0];  // [B,N,D]
  const float* proj = (const float*)d_in[1];  // [N,E]
  const float* Wq   = (const float*)d_in[2];  // [D,D]
  const float* Wk   = (const float*)d_in[3];
  const float* Wv   = (const float*)d_in[4];
  float* out = (float*)d_out;

  short* p = (short*)d_ws;
  short* xtb_qb = p; p += (size_t)B_ * D_ * N_;  // xtb, later qb
  short* xb     = p; p += (size_t)B_ * N_ * D_;
  short* WqT    = p; p += (size_t)D_ * D_;
  short* WkT    = p; p += (size_t)D_ * D_;
  short* WvT    = p; p += (size_t)D_ * D_;
  short* projT  = p; p += (size_t)E_ * N_;
  short* xp     = p; p += (size_t)B_ * E_ * D_;
  short* kpb    = p; p += (size_t)B_ * E_ * D_;
  short* vpT    = p; p += (size_t)B_ * D_ * E_;
  short* xtb = xtb_qb;
  short* qb  = xtb_qb;

  dim3 blkT(32, 8);
  transpose_x_kernel<<<dim3(D_ / 32, N_ / 32, B_), blkT, 0, stream>>>(x, xtb, xb);
  transpose_w_kernel<<<dim3(D_ / 32, D_ / 32, 3), blkT, 0, stream>>>(Wq, Wk, Wv, WqT, WkT, WvT);
  transpose_p_kernel<<<dim3(E_ / 32, N_ / 32, 1), blkT, 0, stream>>>(proj, projT);

  // xp[b] = proj^T @ x[b] — single-pass full-K, no atomics, direct bf16
  xp_kernel<<<256, 256, 0, stream>>>(projT, xtb, xp);

  // q = xb @ W_q — 256^2 8-phase kernel (qb overwrites dead xtb)
  gemm256_bt_kernel<<<dim3(((B_ * N_) / 256) * (D_ / 256)), 512, 0, stream>>>(
      xb, WqT, qb, B_ * N_, D_, D_);

  // k_proj / v_proj^T fused (shared A-fragments)
  gemm_kv_kernel<<<dim3(E_ / 64, D_ / 64, B_), 256, 0, stream>>>(
      xp, WkT, WvT, kpb, vpT);

  attn_kernel<<<dim3(N_ / 128, H_, B_), 512, 0, stream>>>(qb, kpb, vpT, out);
}